// Round 1
// baseline (620.035 us; speedup 1.0000x reference)
//
#include <hip/hip_runtime.h>
#include <hip/hip_bf16.h>
#include <stdint.h>

// Problem constants
#define BB   2
#define TLEN 4096
#define DMm  2048
#define DD   4096
#define WWIN 4
#define DGg  512
#define BT   8192          // B*T
#define DW   16384         // D*W

typedef __attribute__((ext_vector_type(8))) short bf16x8;
typedef __attribute__((ext_vector_type(4))) float f32x4;

__device__ __forceinline__ unsigned short f2bf(float f) {
    union { float f; unsigned u; } c; c.f = f;
    unsigned u = c.u;
    unsigned r = (u + 0x7FFFu + ((u >> 16) & 1u)) >> 16;   // RNE
    return (unsigned short)r;
}

// ---------------- cast f32 -> bf16, 4 elems/thread ----------------
__global__ void cast4_kernel(const float* __restrict__ in,
                             unsigned short* __restrict__ out, int n4) {
    int i = blockIdx.x * blockDim.x + threadIdx.x;
    if (i >= n4) return;
    float4 v = reinterpret_cast<const float4*>(in)[i];
    ushort4 o;
    o.x = f2bf(v.x); o.y = f2bf(v.y); o.z = f2bf(v.z); o.w = f2bf(v.w);
    reinterpret_cast<ushort4*>(out)[i] = o;
}

#define GLDS16(gp, lp)                                                         \
    __builtin_amdgcn_global_load_lds(                                          \
        (__attribute__((address_space(1))) const void*)(gp),                   \
        (__attribute__((address_space(3))) void*)(lp), 16, 0, 0)

// ---------------- GEMM1: h = silu(gen @ w1^T), bf16 out ----------------
// A: [BT][DM] bf16, Bm: [DG][DM] bf16 (row-major = B^T), H: [BT][DG] bf16
__global__ __launch_bounds__(256) void gemm1_silu_kernel(
    const unsigned short* __restrict__ A,
    const unsigned short* __restrict__ Bm,
    unsigned short* __restrict__ H)
{
    __shared__ short smA[128 * 32];
    __shared__ short smB[128 * 32];
    const int m0   = blockIdx.y * 128;
    const int n0   = blockIdx.x * 128;
    const int lane = threadIdx.x & 63;
    const int wave = threadIdx.x >> 6;
    const int wm   = wave >> 1, wn = wave & 1;

    const int c0 = wave * 64 + lane;     // staging chunk ids (16B each)
    const int c1 = c0 + 256;
    const int rA0 = m0 + (c0 >> 2), rA1 = m0 + (c1 >> 2);
    const int rB0 = n0 + (c0 >> 2), rB1 = n0 + (c1 >> 2);
    const int ko0 = (c0 & 3) * 8,  ko1 = (c1 & 3) * 8;

    f32x4 acc[4][4] = {};

    for (int k0 = 0; k0 < DMm; k0 += 32) {
        GLDS16(A  + (size_t)rA0 * DMm + k0 + ko0, smA + wave * 512);
        GLDS16(A  + (size_t)rA1 * DMm + k0 + ko1, smA + 2048 + wave * 512);
        GLDS16(Bm + (size_t)rB0 * DMm + k0 + ko0, smB + wave * 512);
        GLDS16(Bm + (size_t)rB1 * DMm + k0 + ko1, smB + 2048 + wave * 512);
        __syncthreads();

        const int la = lane & 15, ko = (lane >> 4) * 8;
        bf16x8 af[4], bfr[4];
#pragma unroll
        for (int mm = 0; mm < 4; ++mm)
            af[mm] = *reinterpret_cast<const bf16x8*>(&smA[(wm * 64 + mm * 16 + la) * 32 + ko]);
#pragma unroll
        for (int nn = 0; nn < 4; ++nn)
            bfr[nn] = *reinterpret_cast<const bf16x8*>(&smB[(wn * 64 + nn * 16 + la) * 32 + ko]);
#pragma unroll
        for (int mm = 0; mm < 4; ++mm)
#pragma unroll
            for (int nn = 0; nn < 4; ++nn)
                acc[mm][nn] = __builtin_amdgcn_mfma_f32_16x16x32_bf16(
                    af[mm], bfr[nn], acc[mm][nn], 0, 0, 0);
        __syncthreads();
    }

#pragma unroll
    for (int mm = 0; mm < 4; ++mm) {
        int rowB = m0 + wm * 64 + mm * 16 + (lane >> 4) * 4;
#pragma unroll
        for (int nn = 0; nn < 4; ++nn) {
            int colG = n0 + wn * 64 + nn * 16 + (lane & 15);
#pragma unroll
            for (int j = 0; j < 4; ++j) {
                float v = acc[mm][nn][j];
                float s = v / (1.0f + __expf(-v));
                H[(size_t)(rowB + j) * DGg + colG] = f2bf(s);
            }
        }
    }
}

// ------- GEMM2 fused: kflat = h @ w2^T + b2; y = silu(conv(kflat, x)) -------
// Hb: [BT][DG] bf16, W2b: [DW][DG] bf16, b2: [DW] f32, x: [B*T][D] f32
__global__ __launch_bounds__(256) void gemm2_conv_silu_kernel(
    const unsigned short* __restrict__ Hb,
    const unsigned short* __restrict__ W2b,
    const float* __restrict__ b2,
    const float* __restrict__ x,
    float* __restrict__ out)
{
    __shared__ short smA[128 * 32];
    __shared__ short smB[128 * 32];
    const int m0   = blockIdx.y * 128;
    const int n0   = blockIdx.x * 128;
    const int lane = threadIdx.x & 63;
    const int wave = threadIdx.x >> 6;
    const int wm   = wave >> 1, wn = wave & 1;

    const int c0 = wave * 64 + lane;
    const int c1 = c0 + 256;
    const int rA0 = m0 + (c0 >> 2), rA1 = m0 + (c1 >> 2);
    const int rB0 = n0 + (c0 >> 2), rB1 = n0 + (c1 >> 2);
    const int ko0 = (c0 & 3) * 8,  ko1 = (c1 & 3) * 8;

    f32x4 acc[4][4] = {};

    for (int k0 = 0; k0 < DGg; k0 += 32) {
        GLDS16(Hb  + (size_t)rA0 * DGg + k0 + ko0, smA + wave * 512);
        GLDS16(Hb  + (size_t)rA1 * DGg + k0 + ko1, smA + 2048 + wave * 512);
        GLDS16(W2b + (size_t)rB0 * DGg + k0 + ko0, smB + wave * 512);
        GLDS16(W2b + (size_t)rB1 * DGg + k0 + ko1, smB + 2048 + wave * 512);
        __syncthreads();

        const int la = lane & 15, ko = (lane >> 4) * 8;
        bf16x8 af[4], bfr[4];
#pragma unroll
        for (int mm = 0; mm < 4; ++mm)
            af[mm] = *reinterpret_cast<const bf16x8*>(&smA[(wm * 64 + mm * 16 + la) * 32 + ko]);
#pragma unroll
        for (int nn = 0; nn < 4; ++nn)
            bfr[nn] = *reinterpret_cast<const bf16x8*>(&smB[(wn * 64 + nn * 16 + la) * 32 + ko]);
#pragma unroll
        for (int mm = 0; mm < 4; ++mm)
#pragma unroll
            for (int nn = 0; nn < 4; ++nn)
                acc[mm][nn] = __builtin_amdgcn_mfma_f32_16x16x32_bf16(
                    af[mm], bfr[nn], acc[mm][nn], 0, 0, 0);
        __syncthreads();
    }

    // Epilogue: add bias, multiply by shifted x, reduce over w (4-lane group),
    // silu, store. C layout: col = lane&15, row = (lane>>4)*4 + j (m89/m91).
#pragma unroll
    for (int nn = 0; nn < 4; ++nn) {
        int colG = n0 + wn * 64 + nn * 16 + (lane & 15);   // = 4*d + w
        float bias = b2[colG];
        int d = colG >> 2;
        int w = colG & 3;
#pragma unroll
        for (int mm = 0; mm < 4; ++mm) {
            int rowB = m0 + wm * 64 + mm * 16 + (lane >> 4) * 4;
#pragma unroll
            for (int j = 0; j < 4; ++j) {
                int rowG = rowB + j;                 // global token = b*T + t
                int t = rowG & (TLEN - 1);
                int ts = t + w - 3;                  // shifted time, ts<=t<T
                float xv = 0.0f;
                if (ts >= 0) xv = x[(size_t)(rowG + w - 3) * DD + d];
                float p = (acc[mm][nn][j] + bias) * xv;
                p += __shfl_xor(p, 1);
                p += __shfl_xor(p, 2);
                if ((lane & 3) == 0) {
                    float yv = p / (1.0f + __expf(-p));
                    out[(size_t)rowG * DD + d] = yv;
                }
            }
        }
    }
}

extern "C" void kernel_launch(void* const* d_in, const int* in_sizes, int n_in,
                              void* d_out, int out_size, void* d_ws, size_t ws_size,
                              hipStream_t stream) {
    const float* x   = (const float*)d_in[0];
    const float* gen = (const float*)d_in[1];
    const float* w1  = (const float*)d_in[2];
    const float* w2  = (const float*)d_in[3];
    const float* b2  = (const float*)d_in[4];
    float* out = (float*)d_out;

    char* ws = (char*)d_ws;
    size_t off = 0;
    unsigned short* gen_b = (unsigned short*)(ws + off); off += (size_t)BT * DMm * 2;  // 33.6 MB
    unsigned short* w1_b  = (unsigned short*)(ws + off); off += (size_t)DGg * DMm * 2; //  2.1 MB
    unsigned short* w2_b  = (unsigned short*)(ws + off); off += (size_t)DW * DGg * 2;  // 16.8 MB
    unsigned short* h_b   = (unsigned short*)(ws + off); off += (size_t)BT * DGg * 2;  //  8.4 MB

    int n4;
    n4 = BT * DMm / 4;
    cast4_kernel<<<(n4 + 255) / 256, 256, 0, stream>>>(gen, gen_b, n4);
    n4 = DGg * DMm / 4;
    cast4_kernel<<<(n4 + 255) / 256, 256, 0, stream>>>(w1, w1_b, n4);
    n4 = DW * DGg / 4;
    cast4_kernel<<<(n4 + 255) / 256, 256, 0, stream>>>(w2, w2_b, n4);

    gemm1_silu_kernel<<<dim3(DGg / 128, BT / 128), 256, 0, stream>>>(gen_b, w1_b, h_b);
    gemm2_conv_silu_kernel<<<dim3(DW / 128, BT / 128), 256, 0, stream>>>(h_b, w2_b, b2, x, out);
}

// Round 2
// 377.732 us; speedup vs baseline: 1.6415x; 1.6415x over previous
//
#include <hip/hip_runtime.h>
#include <hip/hip_bf16.h>
#include <stdint.h>

// Problem constants
#define BB   2
#define TLEN 4096
#define DMm  2048
#define DD   4096
#define WWIN 4
#define DGg  512
#define BT   8192          // B*T
#define DW   16384         // D*W

typedef __attribute__((ext_vector_type(8))) short bf16x8;
typedef __attribute__((ext_vector_type(4))) float f32x4;

__device__ __forceinline__ unsigned short f2bf(float f) {
    union { float f; unsigned u; } c; c.f = f;
    unsigned u = c.u;
    unsigned r = (u + 0x7FFFu + ((u >> 16) & 1u)) >> 16;   // RNE
    return (unsigned short)r;
}

// ---------------- cast f32 -> bf16, 4 elems/thread ----------------
__global__ void cast4_kernel(const float* __restrict__ in,
                             unsigned short* __restrict__ out, int n4) {
    int i = blockIdx.x * blockDim.x + threadIdx.x;
    if (i >= n4) return;
    float4 v = reinterpret_cast<const float4*>(in)[i];
    ushort4 o;
    o.x = f2bf(v.x); o.y = f2bf(v.y); o.z = f2bf(v.z); o.w = f2bf(v.w);
    reinterpret_cast<ushort4*>(out)[i] = o;
}

#define GLDS16(gp, lp)                                                         \
    __builtin_amdgcn_global_load_lds(                                          \
        (__attribute__((address_space(1))) const void*)(gp),                   \
        (__attribute__((address_space(3))) void*)(lp), 16, 0, 0)

// ---------------- GEMM1: h = silu(gen @ w1^T), bf16 out ----------------
// A: [BT][DM] bf16, Bm: [DG][DM] bf16 (row-major = B^T), H: [BT][DG] bf16
__global__ __launch_bounds__(256) void gemm1_silu_kernel(
    const unsigned short* __restrict__ A,
    const unsigned short* __restrict__ Bm,
    unsigned short* __restrict__ H)
{
    __shared__ short smA[128 * 32];
    __shared__ short smB[128 * 32];
    const int m0   = blockIdx.y * 128;
    const int n0   = blockIdx.x * 128;
    const int lane = threadIdx.x & 63;
    const int wave = threadIdx.x >> 6;
    const int wm   = wave >> 1, wn = wave & 1;

    const int c0 = wave * 64 + lane;     // staging chunk ids (16B each)
    const int c1 = c0 + 256;
    const int rA0 = m0 + (c0 >> 2), rA1 = m0 + (c1 >> 2);
    const int rB0 = n0 + (c0 >> 2), rB1 = n0 + (c1 >> 2);
    const int ko0 = (c0 & 3) * 8,  ko1 = (c1 & 3) * 8;

    f32x4 acc[4][4] = {};

    for (int k0 = 0; k0 < DMm; k0 += 32) {
        GLDS16(A  + (size_t)rA0 * DMm + k0 + ko0, smA + wave * 512);
        GLDS16(A  + (size_t)rA1 * DMm + k0 + ko1, smA + 2048 + wave * 512);
        GLDS16(Bm + (size_t)rB0 * DMm + k0 + ko0, smB + wave * 512);
        GLDS16(Bm + (size_t)rB1 * DMm + k0 + ko1, smB + 2048 + wave * 512);
        __syncthreads();

        const int la = lane & 15, ko = (lane >> 4) * 8;
        bf16x8 af[4], bfr[4];
#pragma unroll
        for (int mm = 0; mm < 4; ++mm)
            af[mm] = *reinterpret_cast<const bf16x8*>(&smA[(wm * 64 + mm * 16 + la) * 32 + ko]);
#pragma unroll
        for (int nn = 0; nn < 4; ++nn)
            bfr[nn] = *reinterpret_cast<const bf16x8*>(&smB[(wn * 64 + nn * 16 + la) * 32 + ko]);
#pragma unroll
        for (int mm = 0; mm < 4; ++mm)
#pragma unroll
            for (int nn = 0; nn < 4; ++nn)
                acc[mm][nn] = __builtin_amdgcn_mfma_f32_16x16x32_bf16(
                    af[mm], bfr[nn], acc[mm][nn], 0, 0, 0);
        __syncthreads();
    }

#pragma unroll
    for (int mm = 0; mm < 4; ++mm) {
        int rowB = m0 + wm * 64 + mm * 16 + (lane >> 4) * 4;
#pragma unroll
        for (int nn = 0; nn < 4; ++nn) {
            int colG = n0 + wn * 64 + nn * 16 + (lane & 15);
#pragma unroll
            for (int j = 0; j < 4; ++j) {
                float v = acc[mm][nn][j];
                float s = v / (1.0f + __expf(-v));
                H[(size_t)(rowB + j) * DGg + colG] = f2bf(s);
            }
        }
    }
}

// ------- GEMM2 fused: kflat = h @ w2^T + b2; y = silu(conv(kflat, x)) -------
// Hb: [BT][DG] bf16, W2b: [DW][DG] bf16, b2: [DW] f32, x: [B*T][D] f32
// Epilogue: x tile staged in LDS (latency hidden under K-loop), w-reduction
// via 4-lane shfl_xor, y routed through LDS for coalesced 128B-row stores.
#define SMX_STRIDE 36   // 32 data + 4 pad -> conflict-free epilogue reads, 16B-align-free scalar writes
#define SMY_STRIDE 33
__global__ __launch_bounds__(256) void gemm2_conv_silu_kernel(
    const unsigned short* __restrict__ Hb,
    const unsigned short* __restrict__ W2b,
    const float* __restrict__ b2,
    const float* __restrict__ x,
    float* __restrict__ out)
{
    __shared__ short smA[128 * 32];
    __shared__ short smB[128 * 32];
    __shared__ float smX[131 * SMX_STRIDE];   // rows m0-3 .. m0+127, 32 d columns
    __shared__ float smY[128 * SMY_STRIDE];

    const int m0   = blockIdx.y * 128;
    const int n0   = blockIdx.x * 128;
    const int d0   = n0 >> 2;
    const int lane = threadIdx.x & 63;
    const int wave = threadIdx.x >> 6;
    const int wm   = wave >> 1, wn = wave & 1;

    // ---- stage x[m0-3 .. m0+127][d0 .. d0+31] into smX (coalesced float4) ----
    // Latency hides under the K-loop; the loop's first __syncthreads orders it.
    for (int c = threadIdx.x; c < 131 * 8; c += 256) {
        int row = c >> 3, q = (c & 7) * 4;
        int rg = m0 - 3 + row;
        float4 v = make_float4(0.f, 0.f, 0.f, 0.f);
        if (rg >= 0 && (rg >> 12) == (m0 >> 12))   // zero across batch boundary
            v = *reinterpret_cast<const float4*>(&x[(size_t)rg * DD + d0 + q]);
        smX[row * SMX_STRIDE + q + 0] = v.x;
        smX[row * SMX_STRIDE + q + 1] = v.y;
        smX[row * SMX_STRIDE + q + 2] = v.z;
        smX[row * SMX_STRIDE + q + 3] = v.w;
    }

    const int c0 = wave * 64 + lane;
    const int c1 = c0 + 256;
    const int rA0 = m0 + (c0 >> 2), rA1 = m0 + (c1 >> 2);
    const int rB0 = n0 + (c0 >> 2), rB1 = n0 + (c1 >> 2);
    const int ko0 = (c0 & 3) * 8,  ko1 = (c1 & 3) * 8;

    f32x4 acc[4][4] = {};

    for (int k0 = 0; k0 < DGg; k0 += 32) {
        GLDS16(Hb  + (size_t)rA0 * DGg + k0 + ko0, smA + wave * 512);
        GLDS16(Hb  + (size_t)rA1 * DGg + k0 + ko1, smA + 2048 + wave * 512);
        GLDS16(W2b + (size_t)rB0 * DGg + k0 + ko0, smB + wave * 512);
        GLDS16(W2b + (size_t)rB1 * DGg + k0 + ko1, smB + 2048 + wave * 512);
        __syncthreads();

        const int la = lane & 15, ko = (lane >> 4) * 8;
        bf16x8 af[4], bfr[4];
#pragma unroll
        for (int mm = 0; mm < 4; ++mm)
            af[mm] = *reinterpret_cast<const bf16x8*>(&smA[(wm * 64 + mm * 16 + la) * 32 + ko]);
#pragma unroll
        for (int nn = 0; nn < 4; ++nn)
            bfr[nn] = *reinterpret_cast<const bf16x8*>(&smB[(wn * 64 + nn * 16 + la) * 32 + ko]);
#pragma unroll
        for (int mm = 0; mm < 4; ++mm)
#pragma unroll
            for (int nn = 0; nn < 4; ++nn)
                acc[mm][nn] = __builtin_amdgcn_mfma_f32_16x16x32_bf16(
                    af[mm], bfr[nn], acc[mm][nn], 0, 0, 0);
        __syncthreads();
    }

    // ---- epilogue: bias, conv multiply (x from LDS), w-reduce, silu -> smY ----
    // C layout: col = lane&15, row = (lane>>4)*4 + j.  colG = 4*d + w, w = lane&3.
    const int w  = lane & 3;
#pragma unroll
    for (int nn = 0; nn < 4; ++nn) {
        int colG = n0 + wn * 64 + nn * 16 + (lane & 15);
        float bias = b2[colG];
        int dl = wn * 16 + nn * 4 + ((lane & 15) >> 2);   // local d in [0,32)
#pragma unroll
        for (int mm = 0; mm < 4; ++mm) {
            int rl0 = wm * 64 + mm * 16 + (lane >> 4) * 4;  // local row
#pragma unroll
            for (int j = 0; j < 4; ++j) {
                // x row needed: rowG + w - 3 -> smX index (rl + j) + w
                float xv = smX[(rl0 + j + w) * SMX_STRIDE + dl];
                float p = (acc[mm][nn][j] + bias) * xv;
                p += __shfl_xor(p, 1);
                p += __shfl_xor(p, 2);
                if ((lane & 3) == 0) {
                    smY[(rl0 + j) * SMY_STRIDE + dl] = p / (1.0f + __expf(-p));
                }
            }
        }
    }
    __syncthreads();

    // ---- coalesced store: 128 rows x 32 floats (128B per row) ----
    for (int c = threadIdx.x; c < 128 * 8; c += 256) {
        int row = c >> 3, q = (c & 7) * 4;
        float4 v;
        v.x = smY[row * SMY_STRIDE + q + 0];
        v.y = smY[row * SMY_STRIDE + q + 1];
        v.z = smY[row * SMY_STRIDE + q + 2];
        v.w = smY[row * SMY_STRIDE + q + 3];
        *reinterpret_cast<float4*>(&out[(size_t)(m0 + row) * DD + d0 + q]) = v;
    }
}

extern "C" void kernel_launch(void* const* d_in, const int* in_sizes, int n_in,
                              void* d_out, int out_size, void* d_ws, size_t ws_size,
                              hipStream_t stream) {
    const float* x   = (const float*)d_in[0];
    const float* gen = (const float*)d_in[1];
    const float* w1  = (const float*)d_in[2];
    const float* w2  = (const float*)d_in[3];
    const float* b2  = (const float*)d_in[4];
    float* out = (float*)d_out;

    char* ws = (char*)d_ws;
    size_t off = 0;
    unsigned short* gen_b = (unsigned short*)(ws + off); off += (size_t)BT * DMm * 2;  // 33.6 MB
    unsigned short* w1_b  = (unsigned short*)(ws + off); off += (size_t)DGg * DMm * 2; //  2.1 MB
    unsigned short* w2_b  = (unsigned short*)(ws + off); off += (size_t)DW * DGg * 2;  // 16.8 MB
    unsigned short* h_b   = (unsigned short*)(ws + off); off += (size_t)BT * DGg * 2;  //  8.4 MB

    int n4;
    n4 = BT * DMm / 4;
    cast4_kernel<<<(n4 + 255) / 256, 256, 0, stream>>>(gen, gen_b, n4);
    n4 = DGg * DMm / 4;
    cast4_kernel<<<(n4 + 255) / 256, 256, 0, stream>>>(w1, w1_b, n4);
    n4 = DW * DGg / 4;
    cast4_kernel<<<(n4 + 255) / 256, 256, 0, stream>>>(w2, w2_b, n4);

    gemm1_silu_kernel<<<dim3(DGg / 128, BT / 128), 256, 0, stream>>>(gen_b, w1_b, h_b);
    gemm2_conv_silu_kernel<<<dim3(DW / 128, BT / 128), 256, 0, stream>>>(h_b, w2_b, b2, x, out);
}

// Round 3
// 330.961 us; speedup vs baseline: 1.8734x; 1.1413x over previous
//
#include <hip/hip_runtime.h>
#include <hip/hip_bf16.h>
#include <stdint.h>

// Problem constants
#define BB   2
#define TLEN 4096
#define DMm  2048
#define DD   4096
#define WWIN 4
#define DGg  512
#define BT   8192          // B*T
#define DW   16384         // D*W

typedef __attribute__((ext_vector_type(8))) short bf16x8;
typedef __attribute__((ext_vector_type(4))) float f32x4;

__device__ __forceinline__ unsigned short f2bf(float f) {
    union { float f; unsigned u; } c; c.f = f;
    unsigned u = c.u;
    unsigned r = (u + 0x7FFFu + ((u >> 16) & 1u)) >> 16;   // RNE
    return (unsigned short)r;
}

// ---------------- cast f32 -> bf16, 4 elems/thread ----------------
__global__ void cast4_kernel(const float* __restrict__ in,
                             unsigned short* __restrict__ out, int n4) {
    int i = blockIdx.x * blockDim.x + threadIdx.x;
    if (i >= n4) return;
    float4 v = reinterpret_cast<const float4*>(in)[i];
    ushort4 o;
    o.x = f2bf(v.x); o.y = f2bf(v.y); o.z = f2bf(v.z); o.w = f2bf(v.w);
    reinterpret_cast<ushort4*>(out)[i] = o;
}

#define GLDS16(gp, lp)                                                         \
    __builtin_amdgcn_global_load_lds(                                          \
        (__attribute__((address_space(1))) const void*)(gp),                   \
        (__attribute__((address_space(3))) void*)(lp), 16, 0, 0)

// ---------------- GEMM1: h = silu(gen @ w1^T), bf16 out ----------------
// A: [BT][DM] bf16, Bm: [DG][DM] bf16 (row-major = B^T), H: [BT][DG] bf16
__global__ __launch_bounds__(256) void gemm1_silu_kernel(
    const unsigned short* __restrict__ A,
    const unsigned short* __restrict__ Bm,
    unsigned short* __restrict__ H)
{
    __shared__ short smA[128 * 32];
    __shared__ short smB[128 * 32];
    const int m0   = blockIdx.y * 128;
    const int n0   = blockIdx.x * 128;
    const int lane = threadIdx.x & 63;
    const int wave = threadIdx.x >> 6;
    const int wm   = wave >> 1, wn = wave & 1;

    const int c0 = wave * 64 + lane;     // staging chunk ids (16B each)
    const int c1 = c0 + 256;
    const int rA0 = m0 + (c0 >> 2), rA1 = m0 + (c1 >> 2);
    const int rB0 = n0 + (c0 >> 2), rB1 = n0 + (c1 >> 2);
    const int ko0 = (c0 & 3) * 8,  ko1 = (c1 & 3) * 8;

    f32x4 acc[4][4] = {};

    for (int k0 = 0; k0 < DMm; k0 += 32) {
        GLDS16(A  + (size_t)rA0 * DMm + k0 + ko0, smA + wave * 512);
        GLDS16(A  + (size_t)rA1 * DMm + k0 + ko1, smA + 2048 + wave * 512);
        GLDS16(Bm + (size_t)rB0 * DMm + k0 + ko0, smB + wave * 512);
        GLDS16(Bm + (size_t)rB1 * DMm + k0 + ko1, smB + 2048 + wave * 512);
        __syncthreads();

        const int la = lane & 15, ko = (lane >> 4) * 8;
        bf16x8 af[4], bfr[4];
#pragma unroll
        for (int mm = 0; mm < 4; ++mm)
            af[mm] = *reinterpret_cast<const bf16x8*>(&smA[(wm * 64 + mm * 16 + la) * 32 + ko]);
#pragma unroll
        for (int nn = 0; nn < 4; ++nn)
            bfr[nn] = *reinterpret_cast<const bf16x8*>(&smB[(wn * 64 + nn * 16 + la) * 32 + ko]);
#pragma unroll
        for (int mm = 0; mm < 4; ++mm)
#pragma unroll
            for (int nn = 0; nn < 4; ++nn)
                acc[mm][nn] = __builtin_amdgcn_mfma_f32_16x16x32_bf16(
                    af[mm], bfr[nn], acc[mm][nn], 0, 0, 0);
        __syncthreads();
    }

#pragma unroll
    for (int mm = 0; mm < 4; ++mm) {
        int rowB = m0 + wm * 64 + mm * 16 + (lane >> 4) * 4;
#pragma unroll
        for (int nn = 0; nn < 4; ++nn) {
            int colG = n0 + wn * 64 + nn * 16 + (lane & 15);
#pragma unroll
            for (int j = 0; j < 4; ++j) {
                float v = acc[mm][nn][j];
                float s = v / (1.0f + __expf(-v));
                H[(size_t)(rowB + j) * DGg + colG] = f2bf(s);
            }
        }
    }
}

// ------- GEMM2 fused: kflat = h @ w2^T + b2; y = silu(conv(kflat, x)) -------
// SWAPPED-OPERAND trick: acc[mm][nn] = mfma(bfr[nn], af[mm], .) computes the
// kflat tile TRANSPOSED: col = lane&15 = token-local, row = (lane>>4)*4+j =
// n-local. Since n = 4*d + w, the 4 conv taps (w=j) live in the register
// index — the w-reduction is 4 in-register FMAs, no shuffles, all lanes store.
#define SMXY_STRIDE 36   // 32 data + 4 pad: epilogue reads/writes <=2-way (free)
__global__ __launch_bounds__(256, 4) void gemm2_conv_silu_kernel(
    const unsigned short* __restrict__ Hb,
    const unsigned short* __restrict__ W2b,
    const float* __restrict__ b2,
    const float* __restrict__ x,
    float* __restrict__ out)
{
    __shared__ short smA[128 * 32];
    __shared__ short smB[128 * 32];
    __shared__ float smXY[131 * SMXY_STRIDE];  // x tile during K-loop/compute, y tile after

    const int m0   = blockIdx.y * 128;
    const int n0   = blockIdx.x * 128;
    const int d0   = n0 >> 2;
    const int lane = threadIdx.x & 63;
    const int wave = threadIdx.x >> 6;
    const int wm   = wave >> 1, wn = wave & 1;
    const int la   = lane & 15, hi = lane >> 4;

    // ---- stage x[m0-3 .. m0+127][d0 .. d0+31] into smXY (coalesced float4) ----
    // Latency hides under the K-loop; the loop's first __syncthreads orders it.
    for (int c = threadIdx.x; c < 131 * 8; c += 256) {
        int row = c >> 3, q = (c & 7) * 4;
        int rg = m0 - 3 + row;
        float4 v = make_float4(0.f, 0.f, 0.f, 0.f);
        if (rg >= 0 && (rg >> 12) == (m0 >> 12))   // zero across batch boundary
            v = *reinterpret_cast<const float4*>(&x[(size_t)rg * DD + d0 + q]);
        *reinterpret_cast<float4*>(&smXY[row * SMXY_STRIDE + q]) = v;
    }

    // ---- hoist b2: per nn one aligned float4 (n_base = 4*d), L2-hot ----
    float4 bb[4];
#pragma unroll
    for (int nn = 0; nn < 4; ++nn) {
        int nbase = n0 + wn * 64 + nn * 16 + hi * 4;
        bb[nn] = *reinterpret_cast<const float4*>(&b2[nbase]);
    }

    const int c0 = wave * 64 + lane;
    const int c1 = c0 + 256;
    const int rA0 = m0 + (c0 >> 2), rA1 = m0 + (c1 >> 2);
    const int rB0 = n0 + (c0 >> 2), rB1 = n0 + (c1 >> 2);
    const int ko0 = (c0 & 3) * 8,  ko1 = (c1 & 3) * 8;

    f32x4 acc[4][4] = {};

    for (int k0 = 0; k0 < DGg; k0 += 32) {
        GLDS16(Hb  + (size_t)rA0 * DGg + k0 + ko0, smA + wave * 512);
        GLDS16(Hb  + (size_t)rA1 * DGg + k0 + ko1, smA + 2048 + wave * 512);
        GLDS16(W2b + (size_t)rB0 * DGg + k0 + ko0, smB + wave * 512);
        GLDS16(W2b + (size_t)rB1 * DGg + k0 + ko1, smB + 2048 + wave * 512);
        __syncthreads();

        const int ko = hi * 8;
        bf16x8 af[4], bfr[4];
#pragma unroll
        for (int mm = 0; mm < 4; ++mm)
            af[mm] = *reinterpret_cast<const bf16x8*>(&smA[(wm * 64 + mm * 16 + la) * 32 + ko]);
#pragma unroll
        for (int nn = 0; nn < 4; ++nn)
            bfr[nn] = *reinterpret_cast<const bf16x8*>(&smB[(wn * 64 + nn * 16 + la) * 32 + ko]);
#pragma unroll
        for (int mm = 0; mm < 4; ++mm)
#pragma unroll
            for (int nn = 0; nn < 4; ++nn)
                acc[mm][nn] = __builtin_amdgcn_mfma_f32_16x16x32_bf16(
                    bfr[nn], af[mm], acc[mm][nn], 0, 0, 0);   // SWAPPED -> C^T
        __syncthreads();
    }

    // ---- epilogue: per (mm,nn) thread owns token tl, channel dl, taps j=0..3 ----
    // y(t,d) = silu( sum_j (kflat[t,4d+j] + b2[4d+j]) * x[t+j-3, d] )
    // smXY row for tap j: (t - (m0-3)) + j - 3 = tl + j, tl = local token.
    float p[4][4];
#pragma unroll
    for (int mm = 0; mm < 4; ++mm) {
        int tl = wm * 64 + mm * 16 + la;
#pragma unroll
        for (int nn = 0; nn < 4; ++nn) {
            int dl = wn * 16 + nn * 4 + hi;
            float s0 = acc[mm][nn][0] + bb[nn].x;
            float s1 = acc[mm][nn][1] + bb[nn].y;
            float s2 = acc[mm][nn][2] + bb[nn].z;
            float s3 = acc[mm][nn][3] + bb[nn].w;
            float pv;
            pv  = s0 * smXY[(tl + 0) * SMXY_STRIDE + dl];
            pv += s1 * smXY[(tl + 1) * SMXY_STRIDE + dl];
            pv += s2 * smXY[(tl + 2) * SMXY_STRIDE + dl];
            pv += s3 * smXY[(tl + 3) * SMXY_STRIDE + dl];
            p[mm][nn] = pv / (1.0f + __expf(-pv));
        }
    }
    __syncthreads();

    // ---- reuse smXY as y tile [128][stride 36] ----
#pragma unroll
    for (int mm = 0; mm < 4; ++mm) {
        int tl = wm * 64 + mm * 16 + la;
#pragma unroll
        for (int nn = 0; nn < 4; ++nn) {
            int dl = wn * 16 + nn * 4 + hi;
            smXY[tl * SMXY_STRIDE + dl] = p[mm][nn];
        }
    }
    __syncthreads();

    // ---- coalesced store: 128 rows x 32 floats (128B per row) ----
    for (int c = threadIdx.x; c < 128 * 8; c += 256) {
        int row = c >> 3, q = (c & 7) * 4;
        float4 v = *reinterpret_cast<const float4*>(&smXY[row * SMXY_STRIDE + q]);
        *reinterpret_cast<float4*>(&out[(size_t)(m0 + row) * DD + d0 + q]) = v;
    }
}

extern "C" void kernel_launch(void* const* d_in, const int* in_sizes, int n_in,
                              void* d_out, int out_size, void* d_ws, size_t ws_size,
                              hipStream_t stream) {
    const float* x   = (const float*)d_in[0];
    const float* gen = (const float*)d_in[1];
    const float* w1  = (const float*)d_in[2];
    const float* w2  = (const float*)d_in[3];
    const float* b2  = (const float*)d_in[4];
    float* out = (float*)d_out;

    char* ws = (char*)d_ws;
    size_t off = 0;
    unsigned short* gen_b = (unsigned short*)(ws + off); off += (size_t)BT * DMm * 2;  // 33.6 MB
    unsigned short* w1_b  = (unsigned short*)(ws + off); off += (size_t)DGg * DMm * 2; //  2.1 MB
    unsigned short* w2_b  = (unsigned short*)(ws + off); off += (size_t)DW * DGg * 2;  // 16.8 MB
    unsigned short* h_b   = (unsigned short*)(ws + off); off += (size_t)BT * DGg * 2;  //  8.4 MB

    int n4;
    n4 = BT * DMm / 4;
    cast4_kernel<<<(n4 + 255) / 256, 256, 0, stream>>>(gen, gen_b, n4);
    n4 = DGg * DMm / 4;
    cast4_kernel<<<(n4 + 255) / 256, 256, 0, stream>>>(w1, w1_b, n4);
    n4 = DW * DGg / 4;
    cast4_kernel<<<(n4 + 255) / 256, 256, 0, stream>>>(w2, w2_b, n4);

    gemm1_silu_kernel<<<dim3(DGg / 128, BT / 128), 256, 0, stream>>>(gen_b, w1_b, h_b);
    gemm2_conv_silu_kernel<<<dim3(DW / 128, BT / 128), 256, 0, stream>>>(h_b, w2_b, b2, x, out);
}

// Round 5
// 292.656 us; speedup vs baseline: 2.1186x; 1.1309x over previous
//
#include <hip/hip_runtime.h>
#include <hip/hip_bf16.h>
#include <stdint.h>

// Problem constants
#define TLEN 4096
#define DMm  2048
#define DD   4096
#define DGg  512
#define BT   8192          // B*T
#define DW   16384         // D*W

typedef __attribute__((ext_vector_type(8))) short bf16x8;
typedef __attribute__((ext_vector_type(4))) float f32x4;

__device__ __forceinline__ unsigned short f2bf(float f) {
    union { float f; unsigned u; } c; c.f = f;
    unsigned u = c.u;
    unsigned r = (u + 0x7FFFu + ((u >> 16) & 1u)) >> 16;   // RNE
    return (unsigned short)r;
}

// ---------------- cast f32 -> bf16, 4 elems/thread ----------------
__global__ void cast4_kernel(const float* __restrict__ in,
                             unsigned short* __restrict__ out, int n4) {
    int i = blockIdx.x * blockDim.x + threadIdx.x;
    if (i >= n4) return;
    float4 v = reinterpret_cast<const float4*>(in)[i];
    ushort4 o;
    o.x = f2bf(v.x); o.y = f2bf(v.y); o.z = f2bf(v.z); o.w = f2bf(v.w);
    reinterpret_cast<ushort4*>(out)[i] = o;
}

#define GLDS16(gp, lp)                                                         \
    __builtin_amdgcn_global_load_lds(                                          \
        (__attribute__((address_space(1))) const void*)(gp),                   \
        (__attribute__((address_space(3))) void*)(lp), 16, 0, 0)

#define VMCNT(n) asm volatile("s_waitcnt vmcnt(" #n ")" ::: "memory")
#define SBAR()   __builtin_amdgcn_s_barrier()
#define SCHED0() __builtin_amdgcn_sched_barrier(0)

// ---------------- GEMM1: h = silu(gen @ w1^T), bf16 out (unchanged) ----------
__global__ __launch_bounds__(256) void gemm1_silu_kernel(
    const unsigned short* __restrict__ A,
    const unsigned short* __restrict__ Bm,
    unsigned short* __restrict__ H)
{
    __shared__ short smA[128 * 32];
    __shared__ short smB[128 * 32];
    const int m0   = blockIdx.y * 128;
    const int n0   = blockIdx.x * 128;
    const int lane = threadIdx.x & 63;
    const int wave = threadIdx.x >> 6;
    const int wm   = wave >> 1, wn = wave & 1;

    const int c0 = wave * 64 + lane;
    const int c1 = c0 + 256;
    const int rA0 = m0 + (c0 >> 2), rA1 = m0 + (c1 >> 2);
    const int rB0 = n0 + (c0 >> 2), rB1 = n0 + (c1 >> 2);
    const int ko0 = (c0 & 3) * 8,  ko1 = (c1 & 3) * 8;

    f32x4 acc[4][4] = {};

    for (int k0 = 0; k0 < DMm; k0 += 32) {
        GLDS16(A  + (size_t)rA0 * DMm + k0 + ko0, smA + wave * 512);
        GLDS16(A  + (size_t)rA1 * DMm + k0 + ko1, smA + 2048 + wave * 512);
        GLDS16(Bm + (size_t)rB0 * DMm + k0 + ko0, smB + wave * 512);
        GLDS16(Bm + (size_t)rB1 * DMm + k0 + ko1, smB + 2048 + wave * 512);
        __syncthreads();

        const int la = lane & 15, ko = (lane >> 4) * 8;
        bf16x8 af[4], bfr[4];
#pragma unroll
        for (int mm = 0; mm < 4; ++mm)
            af[mm] = *reinterpret_cast<const bf16x8*>(&smA[(wm * 64 + mm * 16 + la) * 32 + ko]);
#pragma unroll
        for (int nn = 0; nn < 4; ++nn)
            bfr[nn] = *reinterpret_cast<const bf16x8*>(&smB[(wn * 64 + nn * 16 + la) * 32 + ko]);
#pragma unroll
        for (int mm = 0; mm < 4; ++mm)
#pragma unroll
            for (int nn = 0; nn < 4; ++nn)
                acc[mm][nn] = __builtin_amdgcn_mfma_f32_16x16x32_bf16(
                    af[mm], bfr[nn], acc[mm][nn], 0, 0, 0);
        __syncthreads();
    }

#pragma unroll
    for (int mm = 0; mm < 4; ++mm) {
        int rowB = m0 + wm * 64 + mm * 16 + (lane >> 4) * 4;
#pragma unroll
        for (int nn = 0; nn < 4; ++nn) {
            int colG = n0 + wn * 64 + nn * 16 + (lane & 15);
#pragma unroll
            for (int j = 0; j < 4; ++j) {
                float v = acc[mm][nn][j];
                float s = v / (1.0f + __expf(-v));
                H[(size_t)(rowB + j) * DGg + colG] = f2bf(s);
            }
        }
    }
}

// ===== GEMM2 fused, counted-vmcnt quad-buffered pipeline =====
// D[n][t] = sum_k W2b[n][k] * Hb[t][k]   (n = 4d+w; conv taps w = acc reg idx j)
// Tile: 256 n x 128 t, BK=32, 16 K-tiles. 8 waves (wm 0..3 x wn 0..1),
// wave output 64n x 64t = 4x4 fragments, 16 MFMA + 8 ds_read_b128 per region.
// LDS rows are 64B -> ds_read at row*64 + hi*16 is bank-uniform (no swizzle).
// Region t: {ds_read(par t&3) ; stage tile t+3 -> par (t+3)&3 ; MFMA ;
//            VMCNT(6) ; SBAR}  -- vmcnt BEFORE the barrier so the barrier
// certifies tile t+1 landed for ALL waves (fixes round-4 race).
// LDS map: A quad [4 par][256 rows][64B]      : [0, 65536)
//          B quad [4 par][128 rows][64B]      : [65536, 98304)
//          X f32  [131 rows][68 floats]       : [98304, 133936)
//          Y overlay on A region after loop.
#define LDS_B2 65536
#define LDS_X2 98304

__global__ __launch_bounds__(512, 2) void gemm2_conv_silu_kernel(
    const unsigned short* __restrict__ Hb,
    const unsigned short* __restrict__ W2b,
    const float* __restrict__ b2,
    const float* __restrict__ x,
    float* __restrict__ out)
{
    __shared__ __attribute__((aligned(16))) char lds[133936];
    const int tid  = threadIdx.x;
    const int lane = tid & 63, wave = tid >> 6;
    const int wm   = wave >> 1, wn = wave & 1;
    const int la   = lane & 15, hi = lane >> 4;

    // XCD-aware swizzle (4096 blocks, 4096 % 8 == 0 -> bijective)
    int bid = blockIdx.x;
    int swz = (bid & 7) * 512 + (bid >> 3);
    const int n0 = (swz >> 6) * 256;   // W2 row tile (n = 4d+w)
    const int t0 = (swz & 63) * 128;   // token tile
    const int d0 = n0 >> 2;

    const int srow = lane >> 2;        // staging row within 16-row chunk
    const int scol = (lane & 3) * 8;   // staging col (bf16 elems)

    auto stageA = [&](int tk, int p) {   // 2 loads/thread: 16KB tile
#pragma unroll
        for (int q = 0; q < 2; ++q) {
            int chunk = wave * 2 + q;                        // 0..15
            int row   = chunk * 16 + srow;                   // 0..255
            GLDS16(W2b + (size_t)(n0 + row) * DGg + tk * 32 + scol,
                   lds + p * 16384 + chunk * 1024);
        }
    };
    auto stageB = [&](int tk, int p) {   // 1 load/thread: 8KB tile
        int row = wave * 16 + srow;                          // 0..127
        GLDS16(Hb + (size_t)(t0 + row) * DGg + tk * 32 + scol,
               lds + LDS_B2 + p * 8192 + wave * 1024);
    };

    f32x4 acc[4][4] = {};

    auto region = [&](int t, bool doStage) {
        const int p = t & 3;
        const char* aB = lds + p * 16384 + wm * 4096 + la * 64 + hi * 16;
        const char* bB = lds + LDS_B2 + p * 8192 + wn * 4096 + la * 64 + hi * 16;
        bf16x8 aF[4], bF[4];
#pragma unroll
        for (int m = 0; m < 4; ++m)
            aF[m] = *reinterpret_cast<const bf16x8*>(aB + m * 1024);
#pragma unroll
        for (int nr = 0; nr < 4; ++nr)
            bF[nr] = *reinterpret_cast<const bf16x8*>(bB + nr * 1024);
        if (doStage) { stageA(t + 3, (t + 3) & 3); stageB(t + 3, (t + 3) & 3); }
        SCHED0();
        __builtin_amdgcn_s_setprio(1);
#pragma unroll
        for (int m = 0; m < 4; ++m)
#pragma unroll
            for (int nr = 0; nr < 4; ++nr)
                acc[m][nr] = __builtin_amdgcn_mfma_f32_16x16x32_bf16(
                    aF[m], bF[nr], acc[m][nr], 0, 0, 0);
        __builtin_amdgcn_s_setprio(0);
        SCHED0();
    };

    // ---- prologue: x loads (oldest), stage tiles 0,1,2, x ds_writes ----
    float4 xv[5]; int xc[5];
#pragma unroll
    for (int k = 0; k < 5; ++k) {
        int c = tid + k * 512;                   // < 2096 = 131 rows * 16 chunks
        xc[k] = c;
        float4 v = make_float4(0.f, 0.f, 0.f, 0.f);
        if (c < 2096) {
            int row = c >> 4, q = c & 15;
            int rg = t0 - 3 + row;
            if (rg >= 0 && (rg >> 12) == (t0 >> 12))   // zero across batch boundary
                v = *reinterpret_cast<const float4*>(&x[(size_t)rg * DD + d0 + q * 4]);
        }
        xv[k] = v;
    }
    stageA(0, 0); stageB(0, 0);
    stageA(1, 1); stageB(1, 1);
    stageA(2, 2); stageB(2, 2);
    SCHED0();
#pragma unroll
    for (int k = 0; k < 5; ++k) {
        if (xc[k] < 2096) {
            int row = xc[k] >> 4, q = xc[k] & 15;
            *reinterpret_cast<float4*>(lds + LDS_X2 + row * 272 + q * 16) = xv[k];
        }
    }
    SCHED0();
    VMCNT(6);    // tile 0 landed (mine); barrier certifies for all waves
    SBAR();

    // ---- main loop: 16 regions ----
    for (int t = 0; t < 13; ++t) {
        region(t, true);
        VMCNT(6);      // tile t+1 landed; tiles t+2, t+3 (6 loads) in flight
        SBAR();
    }
    region(13, false); VMCNT(3); SBAR();   // tile 14 landed
    region(14, false); VMCNT(0); SBAR();   // tile 15 landed
    region(15, false);

    __syncthreads();   // all K-loop LDS reads done; Y may overlay A region

    // ---- epilogue: bias + conv taps (reg idx j) + silu -> smY ----
    float4 bb[4];
#pragma unroll
    for (int m = 0; m < 4; ++m)
        bb[m] = *reinterpret_cast<const float4*>(&b2[n0 + wm * 64 + m * 16 + hi * 4]);

    const float* smX = reinterpret_cast<const float*>(lds + LDS_X2);
    float* smY = reinterpret_cast<float*>(lds);
#pragma unroll
    for (int nr = 0; nr < 4; ++nr) {
        int tl = wn * 64 + nr * 16 + la;
#pragma unroll
        for (int m = 0; m < 4; ++m) {
            int dl = wm * 16 + m * 4 + hi;
            float pv =
                  (acc[m][nr][0] + bb[m].x) * smX[(tl + 0) * 68 + dl]
                + (acc[m][nr][1] + bb[m].y) * smX[(tl + 1) * 68 + dl]
                + (acc[m][nr][2] + bb[m].z) * smX[(tl + 2) * 68 + dl]
                + (acc[m][nr][3] + bb[m].w) * smX[(tl + 3) * 68 + dl];
            smY[tl * 68 + dl] = pv / (1.0f + __expf(-pv));
        }
    }
    __syncthreads();

    // ---- coalesced store: 128 rows x 64 f32 (256 B per row) ----
    for (int c = tid; c < 128 * 16; c += 512) {
        int row = c >> 4, q = c & 15;
        float4 v = *reinterpret_cast<const float4*>(&smY[row * 68 + q * 4]);
        *reinterpret_cast<float4*>(&out[(size_t)(t0 + row) * DD + d0 + q * 4]) = v;
    }
}

extern "C" void kernel_launch(void* const* d_in, const int* in_sizes, int n_in,
                              void* d_out, int out_size, void* d_ws, size_t ws_size,
                              hipStream_t stream) {
    const float* x   = (const float*)d_in[0];
    const float* gen = (const float*)d_in[1];
    const float* w1  = (const float*)d_in[2];
    const float* w2  = (const float*)d_in[3];
    const float* b2  = (const float*)d_in[4];
    float* out = (float*)d_out;

    char* ws = (char*)d_ws;
    size_t off = 0;
    unsigned short* gen_b = (unsigned short*)(ws + off); off += (size_t)BT * DMm * 2;
    unsigned short* w1_b  = (unsigned short*)(ws + off); off += (size_t)DGg * DMm * 2;
    unsigned short* w2_b  = (unsigned short*)(ws + off); off += (size_t)DW * DGg * 2;
    unsigned short* h_b   = (unsigned short*)(ws + off); off += (size_t)BT * DGg * 2;

    int n4;
    n4 = BT * DMm / 4;
    cast4_kernel<<<(n4 + 255) / 256, 256, 0, stream>>>(gen, gen_b, n4);
    n4 = DGg * DMm / 4;
    cast4_kernel<<<(n4 + 255) / 256, 256, 0, stream>>>(w1, w1_b, n4);
    n4 = DW * DGg / 4;
    cast4_kernel<<<(n4 + 255) / 256, 256, 0, stream>>>(w2, w2_b, n4);

    gemm1_silu_kernel<<<dim3(DGg / 128, BT / 128), 256, 0, stream>>>(gen_b, w1_b, h_b);
    gemm2_conv_silu_kernel<<<4096, 512, 0, stream>>>(h_b, w2_b, b2, x, out);
}

// Round 6
// 285.798 us; speedup vs baseline: 2.1695x; 1.0240x over previous
//
#include <hip/hip_runtime.h>
#include <hip/hip_bf16.h>
#include <stdint.h>

// Problem constants
#define TLEN 4096
#define DMm  2048
#define DD   4096
#define DGg  512
#define BT   8192          // B*T
#define DW   16384         // D*W

typedef __attribute__((ext_vector_type(8))) short bf16x8;
typedef __attribute__((ext_vector_type(4))) float f32x4;

__device__ __forceinline__ unsigned short f2bf(float f) {
    union { float f; unsigned u; } c; c.f = f;
    unsigned u = c.u;
    unsigned r = (u + 0x7FFFu + ((u >> 16) & 1u)) >> 16;   // RNE
    return (unsigned short)r;
}

// ---------------- cast f32 -> bf16, 4 elems/thread ----------------
__global__ void cast4_kernel(const float* __restrict__ in,
                             unsigned short* __restrict__ out, int n4) {
    int i = blockIdx.x * blockDim.x + threadIdx.x;
    if (i >= n4) return;
    float4 v = reinterpret_cast<const float4*>(in)[i];
    ushort4 o;
    o.x = f2bf(v.x); o.y = f2bf(v.y); o.z = f2bf(v.z); o.w = f2bf(v.w);
    reinterpret_cast<ushort4*>(out)[i] = o;
}

#define GLDS16(gp, lp)                                                         \
    __builtin_amdgcn_global_load_lds(                                          \
        (__attribute__((address_space(1))) const void*)(gp),                   \
        (__attribute__((address_space(3))) void*)(lp), 16, 0, 0)

#define VMCNT(n) asm volatile("s_waitcnt vmcnt(" #n ")" ::: "memory")
#define SBAR()   __builtin_amdgcn_s_barrier()
#define SCHED0() __builtin_amdgcn_sched_barrier(0)

// ---------------- GEMM1: h = silu(gen @ w1^T), bf16 out (unchanged) ----------
__global__ __launch_bounds__(256) void gemm1_silu_kernel(
    const unsigned short* __restrict__ A,
    const unsigned short* __restrict__ Bm,
    unsigned short* __restrict__ H)
{
    __shared__ short smA[128 * 32];
    __shared__ short smB[128 * 32];
    const int m0   = blockIdx.y * 128;
    const int n0   = blockIdx.x * 128;
    const int lane = threadIdx.x & 63;
    const int wave = threadIdx.x >> 6;
    const int wm   = wave >> 1, wn = wave & 1;

    const int c0 = wave * 64 + lane;
    const int c1 = c0 + 256;
    const int rA0 = m0 + (c0 >> 2), rA1 = m0 + (c1 >> 2);
    const int rB0 = n0 + (c0 >> 2), rB1 = n0 + (c1 >> 2);
    const int ko0 = (c0 & 3) * 8,  ko1 = (c1 & 3) * 8;

    f32x4 acc[4][4] = {};

    for (int k0 = 0; k0 < DMm; k0 += 32) {
        GLDS16(A  + (size_t)rA0 * DMm + k0 + ko0, smA + wave * 512);
        GLDS16(A  + (size_t)rA1 * DMm + k0 + ko1, smA + 2048 + wave * 512);
        GLDS16(Bm + (size_t)rB0 * DMm + k0 + ko0, smB + wave * 512);
        GLDS16(Bm + (size_t)rB1 * DMm + k0 + ko1, smB + 2048 + wave * 512);
        __syncthreads();

        const int la = lane & 15, ko = (lane >> 4) * 8;
        bf16x8 af[4], bfr[4];
#pragma unroll
        for (int mm = 0; mm < 4; ++mm)
            af[mm] = *reinterpret_cast<const bf16x8*>(&smA[(wm * 64 + mm * 16 + la) * 32 + ko]);
#pragma unroll
        for (int nn = 0; nn < 4; ++nn)
            bfr[nn] = *reinterpret_cast<const bf16x8*>(&smB[(wn * 64 + nn * 16 + la) * 32 + ko]);
#pragma unroll
        for (int mm = 0; mm < 4; ++mm)
#pragma unroll
            for (int nn = 0; nn < 4; ++nn)
                acc[mm][nn] = __builtin_amdgcn_mfma_f32_16x16x32_bf16(
                    af[mm], bfr[nn], acc[mm][nn], 0, 0, 0);
        __syncthreads();
    }

#pragma unroll
    for (int mm = 0; mm < 4; ++mm) {
        int rowB = m0 + wm * 64 + mm * 16 + (lane >> 4) * 4;
#pragma unroll
        for (int nn = 0; nn < 4; ++nn) {
            int colG = n0 + wn * 64 + nn * 16 + (lane & 15);
#pragma unroll
            for (int j = 0; j < 4; ++j) {
                float v = acc[mm][nn][j];
                float s = v / (1.0f + __expf(-v));
                H[(size_t)(rowB + j) * DGg + colG] = f2bf(s);
            }
        }
    }
}

// ===== GEMM2 fused: 256n x 256t tile, quad-buffered BK=32, swizzled LDS =====
// D[n][t] = sum_k W2b[n][k] * Hb[t][k]   (n = 4d+w; conv taps w = acc reg idx j)
// 8 waves: wm in {0,1} (128 n-rows each) x wn in {0..3} (64 t-cols each).
// Wave: aF[8] x bF[4] -> 32 MFMA : 12 ds_read_b128 per region (1.33x r5 ratio).
// Bank swizzle (64B rows, 4 slots of 16B): phys_slot = log_slot ^ ((row>>1)&3);
// applied at staging via pre-swizzled GLOBAL source col (LDS dest stays linear)
// and at read via slot = hi ^ ((la>>1)&3). 16 lanes -> 8 bank-quads, 2-way.
// Cadence (per-tile loads = 4): region t stages tile t+3; VMCNT(8) before SBAR
// certifies tile t+1 for ALL waves. x rides in registers (9 float4, issued
// oldest in prologue), written to padded LDS after the K-loop.
// LDS: loop phase A[4 par][256][64B] = 64K, B same = 64K  (128 KB)
//      post phase X f32 [259][68] at 0 (70448 B), Y f32 [256][68] at 70448.
#define LDS_B2 65536
#define LDS_Y2 70448

__global__ __launch_bounds__(512, 2) void gemm2_conv_silu_kernel(
    const unsigned short* __restrict__ Hb,
    const unsigned short* __restrict__ W2b,
    const float* __restrict__ b2,
    const float* __restrict__ x,
    float* __restrict__ out)
{
    __shared__ __attribute__((aligned(16))) char lds[140080];
    const int tid  = threadIdx.x;
    const int lane = tid & 63, wave = tid >> 6;
    const int wm   = wave >> 2, wn = wave & 3;
    const int la   = lane & 15, hi = lane >> 4;

    // XCD-aware swizzle (2048 blocks, 2048 % 8 == 0 -> bijective)
    int bid = blockIdx.x;
    int swz = (bid & 7) * 256 + (bid >> 3);
    const int n0 = (swz >> 5) * 256;   // W2 row tile (n = 4d+w), 64 tiles
    const int t0 = (swz & 31) * 256;   // token tile, 32 tiles
    const int d0 = n0 >> 2;

    // staging: lane l covers row (l>>2) of a 16-row chunk, phys slot l&3.
    // source col pre-swizzled so phys slot p holds logical slot p^((row>>1)&3).
    const int srow = lane >> 2;
    const int scol = ((lane & 3) ^ ((srow >> 1) & 3)) * 8;   // bf16 elems

    auto stageA = [&](int tk, int p) {   // 2 loads/thread: 16KB tile (256 rows)
#pragma unroll
        for (int q = 0; q < 2; ++q) {
            int chunk = wave * 2 + q;                        // 0..15
            int row   = chunk * 16 + srow;                   // 0..255
            GLDS16(W2b + (size_t)(n0 + row) * DGg + tk * 32 + scol,
                   lds + p * 16384 + chunk * 1024);
        }
    };
    auto stageB = [&](int tk, int p) {   // 2 loads/thread: 16KB tile (256 rows)
#pragma unroll
        for (int q = 0; q < 2; ++q) {
            int chunk = wave * 2 + q;
            int row   = chunk * 16 + srow;
            GLDS16(Hb + (size_t)(t0 + row) * DGg + tk * 32 + scol,
                   lds + LDS_B2 + p * 16384 + chunk * 1024);
        }
    };

    f32x4 acc[8][4] = {};
    const int slotb = (hi ^ ((la >> 1) & 3)) * 16;   // swizzled 16B slot

    auto region = [&](int t, bool doStage) {
        const int p = t & 3;
        const char* aB = lds + p * 16384 + (wm * 128 + la) * 64 + slotb;
        const char* bB = lds + LDS_B2 + p * 16384 + (wn * 64 + la) * 64 + slotb;
        bf16x8 aF[8], bF[4];
#pragma unroll
        for (int m = 0; m < 8; ++m)
            aF[m] = *reinterpret_cast<const bf16x8*>(aB + m * 1024);
#pragma unroll
        for (int nr = 0; nr < 4; ++nr)
            bF[nr] = *reinterpret_cast<const bf16x8*>(bB + nr * 1024);
        if (doStage) { stageA(t + 3, (t + 3) & 3); stageB(t + 3, (t + 3) & 3); }
        SCHED0();
        __builtin_amdgcn_s_setprio(1);
#pragma unroll
        for (int m = 0; m < 8; ++m)
#pragma unroll
            for (int nr = 0; nr < 4; ++nr)
                acc[m][nr] = __builtin_amdgcn_mfma_f32_16x16x32_bf16(
                    aF[m], bF[nr], acc[m][nr], 0, 0, 0);
        __builtin_amdgcn_s_setprio(0);
        SCHED0();
    };

    // ---- prologue: x loads (oldest, ride in regs), stage tiles 0,1,2 ----
    float4 xv[9];
#pragma unroll
    for (int k = 0; k < 9; ++k) {
        int c = tid + k * 512;                   // < 4144 = 259 rows * 16 chunks
        float4 v = make_float4(0.f, 0.f, 0.f, 0.f);
        if (c < 4144) {
            int row = c >> 4, q = c & 15;
            int rg = t0 - 3 + row;
            if (rg >= 0 && (rg >> 12) == (t0 >> 12))   // zero across batch boundary
                v = *reinterpret_cast<const float4*>(&x[(size_t)rg * DD + d0 + q * 4]);
        }
        xv[k] = v;
    }
    stageA(0, 0); stageB(0, 0);
    stageA(1, 1); stageB(1, 1);
    stageA(2, 2); stageB(2, 2);
    SCHED0();
    VMCNT(8);    // x(9)+tile0(4) drained; tiles 1,2 (8) in flight
    SBAR();

    // ---- main loop: 16 regions, counted vmcnt BEFORE each barrier ----
    for (int t = 0; t < 13; ++t) {
        region(t, true);
        VMCNT(8);      // tile t+1 landed; tiles t+2, t+3 (8 loads) in flight
        SBAR();
    }
    region(13, false); VMCNT(4); SBAR();   // tile 14 landed
    region(14, false); VMCNT(0); SBAR();   // tile 15 landed
    region(15, false);

    __syncthreads();   // all K-loop LDS reads done; overlay X/Y

    // ---- write x regs -> padded LDS f32 [259][68] ----
    float* smX = reinterpret_cast<float*>(lds);
#pragma unroll
    for (int k = 0; k < 9; ++k) {
        int c = tid + k * 512;
        if (c < 4144) {
            int row = c >> 4, q = c & 15;
            *reinterpret_cast<float4*>(&smX[row * 68 + q * 4]) = xv[k];
        }
    }
    __syncthreads();

    // ---- epilogue: bias + conv taps (reg idx j) + silu -> smY ----
    float4 bb[8];
#pragma unroll
    for (int m = 0; m < 8; ++m)
        bb[m] = *reinterpret_cast<const float4*>(&b2[n0 + wm * 128 + m * 16 + hi * 4]);

    float* smY = reinterpret_cast<float*>(lds + LDS_Y2);
#pragma unroll
    for (int nr = 0; nr < 4; ++nr) {
        int tl = wn * 64 + nr * 16 + la;
#pragma unroll
        for (int m = 0; m < 8; ++m) {
            int dl = wm * 32 + m * 4 + hi;
            float pv =
                  (acc[m][nr][0] + bb[m].x) * smX[(tl + 0) * 68 + dl]
                + (acc[m][nr][1] + bb[m].y) * smX[(tl + 1) * 68 + dl]
                + (acc[m][nr][2] + bb[m].z) * smX[(tl + 2) * 68 + dl]
                + (acc[m][nr][3] + bb[m].w) * smX[(tl + 3) * 68 + dl];
            smY[tl * 68 + dl] = pv / (1.0f + __expf(-pv));
        }
    }
    __syncthreads();

    // ---- coalesced store: 256 rows x 64 f32 (256 B per row) ----
    for (int c = tid; c < 256 * 16; c += 512) {
        int row = c >> 4, q = c & 15;
        float4 v = *reinterpret_cast<const float4*>(&smY[row * 68 + q * 4]);
        *reinterpret_cast<float4*>(&out[(size_t)(t0 + row) * DD + d0 + q * 4]) = v;
    }
}

extern "C" void kernel_launch(void* const* d_in, const int* in_sizes, int n_in,
                              void* d_out, int out_size, void* d_ws, size_t ws_size,
                              hipStream_t stream) {
    const float* x   = (const float*)d_in[0];
    const float* gen = (const float*)d_in[1];
    const float* w1  = (const float*)d_in[2];
    const float* w2  = (const float*)d_in[3];
    const float* b2  = (const float*)d_in[4];
    float* out = (float*)d_out;

    char* ws = (char*)d_ws;
    size_t off = 0;
    unsigned short* gen_b = (unsigned short*)(ws + off); off += (size_t)BT * DMm * 2;
    unsigned short* w1_b  = (unsigned short*)(ws + off); off += (size_t)DGg * DMm * 2;
    unsigned short* w2_b  = (unsigned short*)(ws + off); off += (size_t)DW * DGg * 2;
    unsigned short* h_b   = (unsigned short*)(ws + off); off += (size_t)BT * DGg * 2;

    int n4;
    n4 = BT * DMm / 4;
    cast4_kernel<<<(n4 + 255) / 256, 256, 0, stream>>>(gen, gen_b, n4);
    n4 = DGg * DMm / 4;
    cast4_kernel<<<(n4 + 255) / 256, 256, 0, stream>>>(w1, w1_b, n4);
    n4 = DW * DGg / 4;
    cast4_kernel<<<(n4 + 255) / 256, 256, 0, stream>>>(w2, w2_b, n4);

    gemm1_silu_kernel<<<dim3(DGg / 128, BT / 128), 256, 0, stream>>>(gen_b, w1_b, h_b);
    gemm2_conv_silu_kernel<<<2048, 512, 0, stream>>>(h_b, w2_b, b2, x, out);
}